// Round 8
// baseline (616.570 us; speedup 1.0000x reference)
//
#include <hip/hip_runtime.h>
#include <hip/hip_bf16.h>

#define NEG_SLOPE 0.2f

// 4 nodes per 256-thread block, one wave per node. h = x@W (stored bf16 for
// compact gathers), a_s/a_d = h.att (computed in f32 from the exact acc).
template <int FIN, int FOUT>
__global__ __launch_bounds__(256) void node_linear(
    const float* __restrict__ x, const float* __restrict__ W,
    const float* __restrict__ att_s, const float* __restrict__ att_d,
    __hip_bfloat16* __restrict__ h, float* __restrict__ a_s, float* __restrict__ a_d, int n)
{
    __shared__ float xs[4][FIN];
    const int wid = threadIdx.x >> 6;
    const int t = threadIdx.x & 63;
    const int node = blockIdx.x * 4 + wid;
    if (node < n) {
        for (int k = t; k < FIN; k += 64) xs[wid][k] = x[(size_t)node * FIN + k];
    }
    __syncthreads();
    if (node >= n) return;
    float acc = 0.f;
    if (t < FOUT) {
        const float* wp = W + t;  // column t; lanes read contiguous 4B -> coalesced
        #pragma unroll
        for (int k = 0; k < FIN; ++k) acc = fmaf(xs[wid][k], wp[(size_t)k * FOUT], acc);
        h[(size_t)node * FOUT + t] = __float2bfloat16(acc);
    }
    float hs = (t < FOUT) ? acc * att_s[t] : 0.f;
    float hd = (t < FOUT) ? acc * att_d[t] : 0.f;
    #pragma unroll
    for (int o = 32; o > 0; o >>= 1) {
        hs += __shfl_xor(hs, o);
        hd += __shfl_xor(hd, o);
    }
    if (t == 0) { a_s[node] = hs; a_d[node] = hd; }
}

// ---- CSR build, bucket-local for write locality (once per call) ----
// Bucket = 16 consecutive dst nodes. Stage 1: histogram+scatter into bucket
// regions (cursor+data lines L2-resident: ~425KB working set). Stage 2: per-
// bucket LDS counting sort into exact per-node CSR. packed = (dst&15)<<27|src.

__global__ void bucket_hist(const int* __restrict__ edst, int E, int n,
                            int* __restrict__ bhist)
{
    int i = blockIdx.x * blockDim.x + threadIdx.x;
    const int Etot = E + n;
    if (i >= Etot) return;
    int d = (i < E) ? edst[i] : i - E;   // appended self-loops
    atomicAdd(bhist + (d >> 4), 1);
}

__global__ __launch_bounds__(1024) void scan_block(
    const int* __restrict__ cnt, int n, int* __restrict__ row, int* __restrict__ partials)
{
    __shared__ int buf[1024];
    int gid = blockIdx.x * 1024 + threadIdx.x;
    int v = (gid < n) ? cnt[gid] : 0;
    buf[threadIdx.x] = v;
    __syncthreads();
    for (int off = 1; off < 1024; off <<= 1) {
        int t = (threadIdx.x >= off) ? buf[threadIdx.x - off] : 0;
        __syncthreads();
        buf[threadIdx.x] += t;
        __syncthreads();
    }
    if (gid < n) row[gid] = buf[threadIdx.x] - v;       // exclusive
    if (threadIdx.x == 1023) partials[blockIdx.x] = buf[1023];
}

__global__ __launch_bounds__(128) void scan_partials(int* __restrict__ partials, int nb)
{
    __shared__ int buf[128];
    int v = (threadIdx.x < nb) ? partials[threadIdx.x] : 0;
    buf[threadIdx.x] = v;
    __syncthreads();
    for (int off = 1; off < 128; off <<= 1) {
        int t = (threadIdx.x >= off) ? buf[threadIdx.x - off] : 0;
        __syncthreads();
        buf[threadIdx.x] += t;
        __syncthreads();
    }
    if (threadIdx.x < nb) partials[threadIdx.x] = buf[threadIdx.x] - v;  // exclusive
}

__global__ __launch_bounds__(1024) void scan_add(
    int* __restrict__ row, int n, const int* __restrict__ partials)
{
    int gid = blockIdx.x * 1024 + threadIdx.x;
    if (gid < n) row[gid] += partials[blockIdx.x];
}

__global__ void bucket_scatter(const int* __restrict__ esrc, const int* __restrict__ edst,
                               int E, int n, int* __restrict__ bcur, int* __restrict__ packed)
{
    int i = blockIdx.x * blockDim.x + threadIdx.x;
    const int Etot = E + n;
    if (i >= Etot) return;
    int s, d;
    if (i < E) { s = esrc[i]; d = edst[i]; }
    else       { s = d = i - E; }
    int pos = atomicAdd(bcur + (d >> 4), 1);
    packed[pos] = ((d & 15) << 27) | s;
}

// One block per bucket: LDS counting sort of the bucket's edges by local dst.
// Writes exact-CSR col[] and per-node row_end[].
__global__ __launch_bounds__(256) void bucket_sort(
    const int* __restrict__ boff, const int* __restrict__ bcur,
    const int* __restrict__ packed, int* __restrict__ col,
    int* __restrict__ row_end, int n)
{
    const int b = blockIdx.x;
    const int lo = boff[b];
    const int hi = bcur[b];                  // post-scatter cursor == bucket end
    __shared__ int hist[16], cur[16];
    if (threadIdx.x < 16) hist[threadIdx.x] = 0;
    __syncthreads();
    for (int j = lo + threadIdx.x; j < hi; j += 256)
        atomicAdd(&hist[((unsigned)packed[j]) >> 27], 1);
    __syncthreads();
    if (threadIdx.x == 0) {
        int run = lo;
        #pragma unroll
        for (int i = 0; i < 16; ++i) {
            cur[i] = run;
            run += hist[i];
            int node = b * 16 + i;
            if (node < n) row_end[node] = run;
        }
    }
    __syncthreads();
    for (int j = lo + threadIdx.x; j < hi; j += 256) {
        int p = packed[j];
        int pos = atomicAdd(&cur[((unsigned)p) >> 27], 1);
        col[pos] = p & 0x07FFFFFF;
    }
}

// ---- Aggregation: FOUT lanes per node; 8-way unrolled gather loop for MLP.
// h gathered as bf16 (halves L2-miss bytes). Softmax shift-invariance: scores
// are O(10), exp() directly is exact & safe. No atomics.
template <int FOUT>
__global__ __launch_bounds__(256) void gat_aggregate(
    const int* __restrict__ row_end, const int* __restrict__ col,
    const float* __restrict__ a_s, const float* __restrict__ a_d,
    const __hip_bfloat16* __restrict__ h, const float* __restrict__ bias,
    float* __restrict__ outp, int n, int do_relu)
{
    constexpr int NPW = 64 / FOUT;             // nodes per wave
    const int gwave = (blockIdx.x * 256 + threadIdx.x) >> 6;
    const int lane = threadIdx.x & 63;
    const int node = gwave * NPW + lane / FOUT;
    const int f = lane % FOUT;
    if (node >= n) return;
    const int end = row_end[node];
    const int start = (node == 0) ? 0 : row_end[node - 1];
    const float adn = a_d[node];
    float acc = 0.f, den = 0.f;
    int j = start;
    for (; j + 8 <= end; j += 8) {
        int s0 = col[j+0], s1 = col[j+1], s2 = col[j+2], s3 = col[j+3];
        int s4 = col[j+4], s5 = col[j+5], s6 = col[j+6], s7 = col[j+7];
        float e0 = a_s[s0], e1 = a_s[s1], e2 = a_s[s2], e3 = a_s[s3];
        float e4 = a_s[s4], e5 = a_s[s5], e6 = a_s[s6], e7 = a_s[s7];
        float h0 = __bfloat162float(h[(size_t)s0 * FOUT + f]);
        float h1 = __bfloat162float(h[(size_t)s1 * FOUT + f]);
        float h2 = __bfloat162float(h[(size_t)s2 * FOUT + f]);
        float h3 = __bfloat162float(h[(size_t)s3 * FOUT + f]);
        float h4 = __bfloat162float(h[(size_t)s4 * FOUT + f]);
        float h5 = __bfloat162float(h[(size_t)s5 * FOUT + f]);
        float h6 = __bfloat162float(h[(size_t)s6 * FOUT + f]);
        float h7 = __bfloat162float(h[(size_t)s7 * FOUT + f]);
        e0 += adn; e1 += adn; e2 += adn; e3 += adn;
        e4 += adn; e5 += adn; e6 += adn; e7 += adn;
        e0 = (e0 > 0.f) ? e0 : NEG_SLOPE * e0;  e1 = (e1 > 0.f) ? e1 : NEG_SLOPE * e1;
        e2 = (e2 > 0.f) ? e2 : NEG_SLOPE * e2;  e3 = (e3 > 0.f) ? e3 : NEG_SLOPE * e3;
        e4 = (e4 > 0.f) ? e4 : NEG_SLOPE * e4;  e5 = (e5 > 0.f) ? e5 : NEG_SLOPE * e5;
        e6 = (e6 > 0.f) ? e6 : NEG_SLOPE * e6;  e7 = (e7 > 0.f) ? e7 : NEG_SLOPE * e7;
        float p0 = __expf(e0), p1 = __expf(e1), p2 = __expf(e2), p3 = __expf(e3);
        float p4 = __expf(e4), p5 = __expf(e5), p6 = __expf(e6), p7 = __expf(e7);
        den += ((p0 + p1) + (p2 + p3)) + ((p4 + p5) + (p6 + p7));
        acc = fmaf(p0, h0, acc); acc = fmaf(p1, h1, acc);
        acc = fmaf(p2, h2, acc); acc = fmaf(p3, h3, acc);
        acc = fmaf(p4, h4, acc); acc = fmaf(p5, h5, acc);
        acc = fmaf(p6, h6, acc); acc = fmaf(p7, h7, acc);
    }
    for (; j < end; ++j) {
        int s = col[j];
        float e = a_s[s] + adn;
        e = (e > 0.f) ? e : NEG_SLOPE * e;
        float p = __expf(e);
        den += p;
        acc = fmaf(p, __bfloat162float(h[(size_t)s * FOUT + f]), acc);
    }
    float v = acc / den + bias[f];             // self-loop guarantees den > 0
    if (do_relu) v = fmaxf(v, 0.f);
    outp[(size_t)node * FOUT + f] = v;
}

extern "C" void kernel_launch(void* const* d_in, const int* in_sizes, int n_in,
                              void* d_out, int out_size, void* d_ws, size_t ws_size,
                              hipStream_t stream)
{
    const float* x   = (const float*)d_in[0];
    const int* eidx  = (const int*)d_in[1];
    const float* W1  = (const float*)d_in[2];
    const float* as1 = (const float*)d_in[3];
    const float* ad1 = (const float*)d_in[4];
    const float* b1  = (const float*)d_in[5];
    const float* W2  = (const float*)d_in[6];
    const float* as2 = (const float*)d_in[7];
    const float* ad2 = (const float*)d_in[8];
    const float* b2  = (const float*)d_in[9];
    const float* W3  = (const float*)d_in[10];
    const float* as3 = (const float*)d_in[11];
    const float* ad3 = (const float*)d_in[12];
    const float* b3  = (const float*)d_in[13];

    const int fhid = in_sizes[3];        // 64
    const int fin  = in_sizes[2] / fhid; // 128
    const int fo3  = in_sizes[11];       // 32
    const int n    = in_sizes[0] / fin;  // 100000
    const int E    = in_sizes[1] / 2;    // 1,600,000
    const int Etot = E + n;
    const int nbuck = (n + 15) >> 4;     // 6250 buckets of 16 nodes

    const int* esrc = eidx;
    const int* edst = eidx + E;

    float* out = (float*)d_out;               // [n, fo3]
    float* h1  = out + (size_t)n * fo3;       // [n, fhid]
    float* h2  = h1 + (size_t)n * fhid;       // [n, fhid]

    // ws: bhist[nbuck] | boff[nbuck] | bcur[nbuck] | partials[128] |
    //     packed[Etot] | col[Etot] | row_end[n] | h_bf16[n*fhid] | a_s[n] | a_d[n]
    int* bhist    = (int*)d_ws;
    int* boff     = bhist + nbuck;
    int* bcur     = boff + nbuck;
    int* partials = bcur + nbuck;
    int* packed   = partials + 128;
    int* col      = packed + Etot;
    int* row_end  = col + Etot;
    __hip_bfloat16* h = (__hip_bfloat16*)(row_end + n);
    float* a_s    = (float*)(h + (size_t)n * fhid);
    float* a_d    = a_s + n;

    const int EB = (Etot + 255) / 256;
    const int nb2 = (nbuck + 1023) / 1024;   // scan blocks over buckets (7 <= 128)

    // ---- CSR build (shared by all layers) ----
    hipMemsetAsync(bhist, 0, (size_t)nbuck * 4, stream);
    bucket_hist<<<EB, 256, 0, stream>>>(edst, E, n, bhist);
    scan_block<<<nb2, 1024, 0, stream>>>(bhist, nbuck, boff, partials);
    scan_partials<<<1, 128, 0, stream>>>(partials, nb2);
    scan_add<<<nb2, 1024, 0, stream>>>(boff, nbuck, partials);
    hipMemcpyAsync(bcur, boff, (size_t)nbuck * 4, hipMemcpyDeviceToDevice, stream);
    bucket_scatter<<<EB, 256, 0, stream>>>(esrc, edst, E, n, bcur, packed);
    bucket_sort<<<nbuck, 256, 0, stream>>>(boff, bcur, packed, col, row_end, n);

    const int NLB = (n + 3) / 4;              // node_linear blocks
    const int AGG64 = (n + 3) / 4;            // 4 nodes / 256-thread block
    const int AGG32 = (n + 7) / 8;            // 8 nodes / 256-thread block

    // ---- Layer 1: x[128] -> h1[64], relu ----
    node_linear<128, 64><<<NLB, 256, 0, stream>>>(x, W1, as1, ad1, h, a_s, a_d, n);
    gat_aggregate<64><<<AGG64, 256, 0, stream>>>(row_end, col, a_s, a_d, h, b1, h1, n, 1);

    // ---- Layer 2: h1[64] -> h2[64], relu ----
    node_linear<64, 64><<<NLB, 256, 0, stream>>>(h1, W2, as2, ad2, h, a_s, a_d, n);
    gat_aggregate<64><<<AGG64, 256, 0, stream>>>(row_end, col, a_s, a_d, h, b2, h2, n, 1);

    // ---- Layer 3: h2[64] -> out[32], no relu ----
    node_linear<64, 32><<<NLB, 256, 0, stream>>>(h2, W3, as3, ad3, h, a_s, a_d, n);
    gat_aggregate<32><<<AGG32, 256, 0, stream>>>(row_end, col, a_s, a_d, h, b3, out, n, 0);
}

// Round 9
// 490.822 us; speedup vs baseline: 1.2562x; 1.2562x over previous
//
#include <hip/hip_runtime.h>
#include <hip/hip_bf16.h>

#define NEG_SLOPE 0.2f

__device__ __forceinline__ unsigned short bf16bits(float f) {
    __hip_bfloat16 t = __float2bfloat16(f);
    return *reinterpret_cast<unsigned short*>(&t);
}

// Tiled GEMM node transform: block of 256 threads computes a [NB x FOUT] tile
// of h = x@W. Each thread: 4 nodes x 4 features in registers (16 FMA per k).
// x tile staged in LDS (padded rows); W streamed as float4 from L1/L2.
// Also computes a_s/a_d via in-wave shfl reduction, writes h as packed bf16.
template <int FIN, int FOUT>
__global__ __launch_bounds__(256) void node_linear(
    const float* __restrict__ x, const float* __restrict__ W,
    const float* __restrict__ att_s, const float* __restrict__ att_d,
    __hip_bfloat16* __restrict__ h, float* __restrict__ a_s, float* __restrict__ a_d, int n)
{
    constexpr int FG = FOUT / 4;          // feature groups (4 features each)
    constexpr int NG = 256 / FG;          // node groups (4 nodes each)
    constexpr int NB = NG * 4;            // nodes per block
    constexpr int RS = FIN + 4;           // padded row stride (floats, 16B-aligned)
    __shared__ float xs[NB * RS];

    const int tid = threadIdx.x;
    const int base = blockIdx.x * NB;

    // Stage x tile: coalesced float4 reads, row-major padded LDS.
    constexpr int CNT = NB * FIN / 4 / 256;
    #pragma unroll
    for (int i = 0; i < CNT; ++i) {
        int f4 = tid + 256 * i;
        int node = f4 / (FIN / 4);
        int kk = f4 % (FIN / 4);
        float4 v = make_float4(0.f, 0.f, 0.f, 0.f);
        if (base + node < n) v = *(const float4*)(x + (size_t)(base + node) * FIN + kk * 4);
        *(float4*)(xs + node * RS + kk * 4) = v;
    }
    __syncthreads();

    const int fg = tid % FG;              // feature block [fg*4, fg*4+4)
    const int ng = tid / FG;              // node block   [ng*4, ng*4+4)
    const float* wp = W + fg * 4;
    const float* xr0 = xs + (ng * 4 + 0) * RS;
    const float* xr1 = xs + (ng * 4 + 1) * RS;
    const float* xr2 = xs + (ng * 4 + 2) * RS;
    const float* xr3 = xs + (ng * 4 + 3) * RS;

    float a00=0,a01=0,a02=0,a03=0, a10=0,a11=0,a12=0,a13=0;
    float a20=0,a21=0,a22=0,a23=0, a30=0,a31=0,a32=0,a33=0;
    #pragma unroll 4
    for (int k = 0; k < FIN; ++k) {
        float4 w = *(const float4*)(wp + (size_t)k * FOUT);
        float x0 = xr0[k], x1 = xr1[k], x2 = xr2[k], x3 = xr3[k];
        a00 = fmaf(x0, w.x, a00); a01 = fmaf(x0, w.y, a01);
        a02 = fmaf(x0, w.z, a02); a03 = fmaf(x0, w.w, a03);
        a10 = fmaf(x1, w.x, a10); a11 = fmaf(x1, w.y, a11);
        a12 = fmaf(x1, w.z, a12); a13 = fmaf(x1, w.w, a13);
        a20 = fmaf(x2, w.x, a20); a21 = fmaf(x2, w.y, a21);
        a22 = fmaf(x2, w.z, a22); a23 = fmaf(x2, w.w, a23);
        a30 = fmaf(x3, w.x, a30); a31 = fmaf(x3, w.y, a31);
        a32 = fmaf(x3, w.z, a32); a33 = fmaf(x3, w.w, a33);
    }

    const float4 ats = *(const float4*)(att_s + fg * 4);
    const float4 atd = *(const float4*)(att_d + fg * 4);
    float acc[4][4] = {{a00,a01,a02,a03},{a10,a11,a12,a13},
                       {a20,a21,a22,a23},{a30,a31,a32,a33}};
    #pragma unroll
    for (int i = 0; i < 4; ++i) {
        int node = base + ng * 4 + i;
        // attention partials, reduced across the FG lanes sharing this node
        float ps = acc[i][0]*ats.x + acc[i][1]*ats.y + acc[i][2]*ats.z + acc[i][3]*ats.w;
        float pd = acc[i][0]*atd.x + acc[i][1]*atd.y + acc[i][2]*atd.z + acc[i][3]*atd.w;
        #pragma unroll
        for (int o = FG / 2; o > 0; o >>= 1) {
            ps += __shfl_xor(ps, o);
            pd += __shfl_xor(pd, o);
        }
        if (fg == 0 && node < n) { a_s[node] = ps; a_d[node] = pd; }
        // packed bf16 h write: 8B per (node, 4 features), coalesced across fg
        if (node < n) {
            unsigned w0 = (unsigned)bf16bits(acc[i][0]) | ((unsigned)bf16bits(acc[i][1]) << 16);
            unsigned w1 = (unsigned)bf16bits(acc[i][2]) | ((unsigned)bf16bits(acc[i][3]) << 16);
            uint2 pk; pk.x = w0; pk.y = w1;
            *reinterpret_cast<uint2*>(h + (size_t)node * FOUT + fg * 4) = pk;
        }
    }
}

// ---- CSR build, bucket-local for write locality (once per call) ----

__global__ void bucket_hist(const int* __restrict__ edst, int E, int n,
                            int* __restrict__ bhist)
{
    int i = blockIdx.x * blockDim.x + threadIdx.x;
    const int Etot = E + n;
    if (i >= Etot) return;
    int d = (i < E) ? edst[i] : i - E;   // appended self-loops
    atomicAdd(bhist + (d >> 4), 1);
}

__global__ __launch_bounds__(1024) void scan_block(
    const int* __restrict__ cnt, int n, int* __restrict__ row, int* __restrict__ partials)
{
    __shared__ int buf[1024];
    int gid = blockIdx.x * 1024 + threadIdx.x;
    int v = (gid < n) ? cnt[gid] : 0;
    buf[threadIdx.x] = v;
    __syncthreads();
    for (int off = 1; off < 1024; off <<= 1) {
        int t = (threadIdx.x >= off) ? buf[threadIdx.x - off] : 0;
        __syncthreads();
        buf[threadIdx.x] += t;
        __syncthreads();
    }
    if (gid < n) row[gid] = buf[threadIdx.x] - v;       // exclusive
    if (threadIdx.x == 1023) partials[blockIdx.x] = buf[1023];
}

__global__ __launch_bounds__(128) void scan_partials(int* __restrict__ partials, int nb)
{
    __shared__ int buf[128];
    int v = (threadIdx.x < nb) ? partials[threadIdx.x] : 0;
    buf[threadIdx.x] = v;
    __syncthreads();
    for (int off = 1; off < 128; off <<= 1) {
        int t = (threadIdx.x >= off) ? buf[threadIdx.x - off] : 0;
        __syncthreads();
        buf[threadIdx.x] += t;
        __syncthreads();
    }
    if (threadIdx.x < nb) partials[threadIdx.x] = buf[threadIdx.x] - v;  // exclusive
}

__global__ __launch_bounds__(1024) void scan_add(
    int* __restrict__ row, int n, const int* __restrict__ partials)
{
    int gid = blockIdx.x * 1024 + threadIdx.x;
    if (gid < n) row[gid] += partials[blockIdx.x];
}

__global__ void bucket_scatter(const int* __restrict__ esrc, const int* __restrict__ edst,
                               int E, int n, int* __restrict__ bcur, int* __restrict__ packed)
{
    int i = blockIdx.x * blockDim.x + threadIdx.x;
    const int Etot = E + n;
    if (i >= Etot) return;
    int s, d;
    if (i < E) { s = esrc[i]; d = edst[i]; }
    else       { s = d = i - E; }
    int pos = atomicAdd(bcur + (d >> 4), 1);
    packed[pos] = ((d & 15) << 27) | s;
}

__global__ __launch_bounds__(256) void bucket_sort(
    const int* __restrict__ boff, const int* __restrict__ bcur,
    const int* __restrict__ packed, int* __restrict__ col,
    int* __restrict__ row_end, int n)
{
    const int b = blockIdx.x;
    const int lo = boff[b];
    const int hi = bcur[b];                  // post-scatter cursor == bucket end
    __shared__ int hist[16], cur[16];
    if (threadIdx.x < 16) hist[threadIdx.x] = 0;
    __syncthreads();
    for (int j = lo + threadIdx.x; j < hi; j += 256)
        atomicAdd(&hist[((unsigned)packed[j]) >> 27], 1);
    __syncthreads();
    if (threadIdx.x == 0) {
        int run = lo;
        #pragma unroll
        for (int i = 0; i < 16; ++i) {
            cur[i] = run;
            run += hist[i];
            int node = b * 16 + i;
            if (node < n) row_end[node] = run;
        }
    }
    __syncthreads();
    for (int j = lo + threadIdx.x; j < hi; j += 256) {
        int p = packed[j];
        int pos = atomicAdd(&cur[((unsigned)p) >> 27], 1);
        col[pos] = p & 0x07FFFFFF;
    }
}

// ---- Aggregation: FOUT lanes per node; 8-way unrolled gather loop for MLP.
// h gathered as bf16. Softmax shift-invariance: scores are O(10), exp() direct.
template <int FOUT>
__global__ __launch_bounds__(256) void gat_aggregate(
    const int* __restrict__ row_end, const int* __restrict__ col,
    const float* __restrict__ a_s, const float* __restrict__ a_d,
    const __hip_bfloat16* __restrict__ h, const float* __restrict__ bias,
    float* __restrict__ outp, int n, int do_relu)
{
    constexpr int NPW = 64 / FOUT;             // nodes per wave
    const int gwave = (blockIdx.x * 256 + threadIdx.x) >> 6;
    const int lane = threadIdx.x & 63;
    const int node = gwave * NPW + lane / FOUT;
    const int f = lane % FOUT;
    if (node >= n) return;
    const int end = row_end[node];
    const int start = (node == 0) ? 0 : row_end[node - 1];
    const float adn = a_d[node];
    float acc = 0.f, den = 0.f;
    int j = start;
    for (; j + 8 <= end; j += 8) {
        int s0 = col[j+0], s1 = col[j+1], s2 = col[j+2], s3 = col[j+3];
        int s4 = col[j+4], s5 = col[j+5], s6 = col[j+6], s7 = col[j+7];
        float e0 = a_s[s0], e1 = a_s[s1], e2 = a_s[s2], e3 = a_s[s3];
        float e4 = a_s[s4], e5 = a_s[s5], e6 = a_s[s6], e7 = a_s[s7];
        float h0 = __bfloat162float(h[(size_t)s0 * FOUT + f]);
        float h1 = __bfloat162float(h[(size_t)s1 * FOUT + f]);
        float h2 = __bfloat162float(h[(size_t)s2 * FOUT + f]);
        float h3 = __bfloat162float(h[(size_t)s3 * FOUT + f]);
        float h4 = __bfloat162float(h[(size_t)s4 * FOUT + f]);
        float h5 = __bfloat162float(h[(size_t)s5 * FOUT + f]);
        float h6 = __bfloat162float(h[(size_t)s6 * FOUT + f]);
        float h7 = __bfloat162float(h[(size_t)s7 * FOUT + f]);
        e0 += adn; e1 += adn; e2 += adn; e3 += adn;
        e4 += adn; e5 += adn; e6 += adn; e7 += adn;
        e0 = (e0 > 0.f) ? e0 : NEG_SLOPE * e0;  e1 = (e1 > 0.f) ? e1 : NEG_SLOPE * e1;
        e2 = (e2 > 0.f) ? e2 : NEG_SLOPE * e2;  e3 = (e3 > 0.f) ? e3 : NEG_SLOPE * e3;
        e4 = (e4 > 0.f) ? e4 : NEG_SLOPE * e4;  e5 = (e5 > 0.f) ? e5 : NEG_SLOPE * e5;
        e6 = (e6 > 0.f) ? e6 : NEG_SLOPE * e6;  e7 = (e7 > 0.f) ? e7 : NEG_SLOPE * e7;
        float p0 = __expf(e0), p1 = __expf(e1), p2 = __expf(e2), p3 = __expf(e3);
        float p4 = __expf(e4), p5 = __expf(e5), p6 = __expf(e6), p7 = __expf(e7);
        den += ((p0 + p1) + (p2 + p3)) + ((p4 + p5) + (p6 + p7));
        acc = fmaf(p0, h0, acc); acc = fmaf(p1, h1, acc);
        acc = fmaf(p2, h2, acc); acc = fmaf(p3, h3, acc);
        acc = fmaf(p4, h4, acc); acc = fmaf(p5, h5, acc);
        acc = fmaf(p6, h6, acc); acc = fmaf(p7, h7, acc);
    }
    for (; j < end; ++j) {
        int s = col[j];
        float e = a_s[s] + adn;
        e = (e > 0.f) ? e : NEG_SLOPE * e;
        float p = __expf(e);
        den += p;
        acc = fmaf(p, __bfloat162float(h[(size_t)s * FOUT + f]), acc);
    }
    float v = acc / den + bias[f];             // self-loop guarantees den > 0
    if (do_relu) v = fmaxf(v, 0.f);
    outp[(size_t)node * FOUT + f] = v;
}

extern "C" void kernel_launch(void* const* d_in, const int* in_sizes, int n_in,
                              void* d_out, int out_size, void* d_ws, size_t ws_size,
                              hipStream_t stream)
{
    const float* x   = (const float*)d_in[0];
    const int* eidx  = (const int*)d_in[1];
    const float* W1  = (const float*)d_in[2];
    const float* as1 = (const float*)d_in[3];
    const float* ad1 = (const float*)d_in[4];
    const float* b1  = (const float*)d_in[5];
    const float* W2  = (const float*)d_in[6];
    const float* as2 = (const float*)d_in[7];
    const float* ad2 = (const float*)d_in[8];
    const float* b2  = (const float*)d_in[9];
    const float* W3  = (const float*)d_in[10];
    const float* as3 = (const float*)d_in[11];
    const float* ad3 = (const float*)d_in[12];
    const float* b3  = (const float*)d_in[13];

    const int fhid = in_sizes[3];        // 64
    const int fin  = in_sizes[2] / fhid; // 128
    const int fo3  = in_sizes[11];       // 32
    const int n    = in_sizes[0] / fin;  // 100000
    const int E    = in_sizes[1] / 2;    // 1,600,000
    const int Etot = E + n;
    const int nbuck = (n + 15) >> 4;     // 6250 buckets of 16 nodes

    const int* esrc = eidx;
    const int* edst = eidx + E;

    float* out = (float*)d_out;               // [n, fo3]
    float* h1  = out + (size_t)n * fo3;       // [n, fhid]
    float* h2  = h1 + (size_t)n * fhid;       // [n, fhid]

    // ws: bhist[nbuck] | boff[nbuck] | bcur[nbuck] | partials[128] |
    //     packed[Etot] | col[Etot] | row_end[n] | h_bf16[n*fhid] | a_s[n] | a_d[n]
    int* bhist    = (int*)d_ws;
    int* boff     = bhist + nbuck;
    int* bcur     = boff + nbuck;
    int* partials = bcur + nbuck;
    int* packed   = partials + 128;
    int* col      = packed + Etot;
    int* row_end  = col + Etot;
    __hip_bfloat16* h = (__hip_bfloat16*)(row_end + n);
    float* a_s    = (float*)(h + (size_t)n * fhid);
    float* a_d    = a_s + n;

    const int EB = (Etot + 255) / 256;
    const int nb2 = (nbuck + 1023) / 1024;

    // ---- CSR build (shared by all layers) ----
    hipMemsetAsync(bhist, 0, (size_t)nbuck * 4, stream);
    bucket_hist<<<EB, 256, 0, stream>>>(edst, E, n, bhist);
    scan_block<<<nb2, 1024, 0, stream>>>(bhist, nbuck, boff, partials);
    scan_partials<<<1, 128, 0, stream>>>(partials, nb2);
    scan_add<<<nb2, 1024, 0, stream>>>(boff, nbuck, partials);
    hipMemcpyAsync(bcur, boff, (size_t)nbuck * 4, hipMemcpyDeviceToDevice, stream);
    bucket_scatter<<<EB, 256, 0, stream>>>(esrc, edst, E, n, bcur, packed);
    bucket_sort<<<nbuck, 256, 0, stream>>>(boff, bcur, packed, col, row_end, n);

    const int NLB64  = (n + 63) / 64;         // node_linear blocks, NB=64 (FOUT=64)
    const int NLB128 = (n + 127) / 128;       // node_linear blocks, NB=128 (FOUT=32)
    const int AGG64 = (n + 3) / 4;            // 4 nodes / 256-thread block
    const int AGG32 = (n + 7) / 8;            // 8 nodes / 256-thread block

    // ---- Layer 1: x[128] -> h1[64], relu ----
    node_linear<128, 64><<<NLB64, 256, 0, stream>>>(x, W1, as1, ad1, h, a_s, a_d, n);
    gat_aggregate<64><<<AGG64, 256, 0, stream>>>(row_end, col, a_s, a_d, h, b1, h1, n, 1);

    // ---- Layer 2: h1[64] -> h2[64], relu ----
    node_linear<64, 64><<<NLB64, 256, 0, stream>>>(h1, W2, as2, ad2, h, a_s, a_d, n);
    gat_aggregate<64><<<AGG64, 256, 0, stream>>>(row_end, col, a_s, a_d, h, b2, h2, n, 1);

    // ---- Layer 3: h2[64] -> out[32], no relu ----
    node_linear<64, 32><<<NLB128, 256, 0, stream>>>(h2, W3, as3, ad3, h, a_s, a_d, n);
    gat_aggregate<32><<<AGG32, 256, 0, stream>>>(row_end, col, a_s, a_d, h, b3, out, n, 0);
}